// Round 5
// baseline (12212.325 us; speedup 1.0000x reference)
//
#include <hip/hip_runtime.h>
#include <math.h>

#define E   512
#define E3  1536
#define NH  8
#define FF  32
#define NL  3
#define NV  32000
#define NB  128
#define NT  16

// ---------------------------------------------------------------- pe table
__global__ void pe_init_kernel(float* __restrict__ pe) {
    int i = blockIdx.x;
    for (int e = threadIdx.x; e < E; e += blockDim.x) {
        int k = e >> 1;
        double dv = exp((double)(2 * k) * (-log(10000.0) / (double)E));
        double arg = (double)i * dv;
        pe[i * E + e] = (e & 1) ? (float)cos(arg) : (float)sin(arg);
    }
}

// ------------------------------------------------------- tok_before row 0
__global__ void init_tok_kernel(float* __restrict__ tb, const float* __restrict__ emb) {
    int b = blockIdx.x;
    for (int e = threadIdx.x; e < E; e += blockDim.x)
        tb[(size_t)b * E + e] = emb[(size_t)1 * E + e];  // SOS = 1
}

// ---- cross-attn constant: ca_const[l][b] = ((cur_room @ Wv^T + bv) @ Wout^T + bout)
// (KV len 1 -> softmax == 1 -> pure V-projection). grid (NB, NL), 256 thr.
__global__ __launch_bounds__(256) void ca_setup_kernel(
    const float* __restrict__ cur_room,
    const float* __restrict__ ca_in_w, const float* __restrict__ ca_in_b,
    const float* __restrict__ ca_out_w, const float* __restrict__ ca_out_b,
    float* __restrict__ ca_const)
{
    const int b = blockIdx.x, l = blockIdx.y, t = threadIdx.x;
    __shared__ float xl[E];
    __shared__ float hv[E];
    for (int e = t; e < E; e += 256) xl[e] = cur_room[(size_t)b * E + e];
    __syncthreads();
    const float* wv = ca_in_w + ((size_t)l * E3 + 2 * E) * E;
    const float* bv = ca_in_b + (size_t)l * E3 + 2 * E;
    for (int c = t; c < E; c += 256) {
        float s = bv[c];
        const float* wr = wv + (size_t)c * E;
        for (int k = 0; k < E; ++k) s += xl[k] * wr[k];
        hv[c] = s;
    }
    __syncthreads();
    const float* wo = ca_out_w + (size_t)l * E * E;
    for (int c = t; c < E; c += 256) {
        float s = ca_out_b[(size_t)l * E + c];
        const float* wr = wo + (size_t)c * E;
        for (int k = 0; k < E; ++k) s += hv[k] * wr[k];
        ca_const[((size_t)l * NB + b) * E + c] = s;
    }
}

// ---------------------------------------------------------------- GEMM v4
// C_partial[z] = A[M slice] @ W[N slice]^T, tile 128x128, 256 thr, 8x8/thread.
// M%128==0, N%128==0, KC%16==0. Partial z -> C + z*CS. No bias (consumers add).
// Tiles with n0 < E (Q section) and m0 < skipm are skipped (l2 optimization).
__global__ __launch_bounds__(256) void gemm_v4_kernel(
    const float* __restrict__ A, const float* __restrict__ W,
    float* __restrict__ C, int N, int K, int KC, size_t CS, int skipm)
{
    const int n0 = blockIdx.x * 128;
    const int m0 = blockIdx.y * 128;
    if (n0 < E && m0 < skipm) return;
    __shared__ float As[16][132];
    __shared__ float Bs[16][132];
    const int tid = threadIdx.x;
    const int kc0 = blockIdx.z * KC;
    const int tx = tid & 15, ty = tid >> 4;
    const int sr = tid >> 1;
    const int sc = (tid & 1) * 8;

    const float* Ap = A + (size_t)(m0 + sr) * K + kc0 + sc;
    const float* Wp = W + (size_t)(n0 + sr) * K + kc0 + sc;
    float4 pa0 = *(const float4*)Ap;
    float4 pa1 = *(const float4*)(Ap + 4);
    float4 pb0 = *(const float4*)Wp;
    float4 pb1 = *(const float4*)(Wp + 4);

    float acc[8][8] = {};
    const int nkt = KC >> 4;
    for (int kt = 0; kt < nkt; ++kt) {
        __syncthreads();
        As[sc + 0][sr] = pa0.x; As[sc + 1][sr] = pa0.y; As[sc + 2][sr] = pa0.z; As[sc + 3][sr] = pa0.w;
        As[sc + 4][sr] = pa1.x; As[sc + 5][sr] = pa1.y; As[sc + 6][sr] = pa1.z; As[sc + 7][sr] = pa1.w;
        Bs[sc + 0][sr] = pb0.x; Bs[sc + 1][sr] = pb0.y; Bs[sc + 2][sr] = pb0.z; Bs[sc + 3][sr] = pb0.w;
        Bs[sc + 4][sr] = pb1.x; Bs[sc + 5][sr] = pb1.y; Bs[sc + 6][sr] = pb1.z; Bs[sc + 7][sr] = pb1.w;
        __syncthreads();
        if (kt + 1 < nkt) {
            const int off = 16 * (kt + 1);
            pa0 = *(const float4*)(Ap + off);
            pa1 = *(const float4*)(Ap + off + 4);
            pb0 = *(const float4*)(Wp + off);
            pb1 = *(const float4*)(Wp + off + 4);
        }
#pragma unroll
        for (int k = 0; k < 16; ++k) {
            float a[8], b[8];
            *(float4*)&a[0] = *(const float4*)&As[k][ty * 4];
            *(float4*)&a[4] = *(const float4*)&As[k][64 + ty * 4];
            *(float4*)&b[0] = *(const float4*)&Bs[k][tx * 4];
            *(float4*)&b[4] = *(const float4*)&Bs[k][64 + tx * 4];
#pragma unroll
            for (int i = 0; i < 8; ++i)
#pragma unroll
                for (int jj = 0; jj < 8; ++jj)
                    acc[i][jj] += a[i] * b[jj];
        }
    }
    float* Co = C + (size_t)blockIdx.z * CS;
#pragma unroll
    for (int ih = 0; ih < 2; ++ih)
#pragma unroll
        for (int i = 0; i < 4; ++i) {
            const int m = m0 + ih * 64 + ty * 4 + i;
#pragma unroll
            for (int jh = 0; jh < 2; ++jh) {
                const int n = n0 + jh * 64 + tx * 4;
                float4 o;
                o.x = acc[ih * 4 + i][jh * 4 + 0];
                o.y = acc[ih * 4 + i][jh * 4 + 1];
                o.z = acc[ih * 4 + i][jh * 4 + 2];
                o.w = acc[ih * 4 + i][jh * 4 + 3];
                *(float4*)&Co[(size_t)m * N + n] = o;
            }
        }
}

// ------------------- fused: attention + out-proj + (LN, +ca, LN, FFN, LN)
// grid (2, NB): block (j, b) handles rows {s : s % 2 == j} of batch b.
// KIND 0: layer0 (qkv0 combined cache + 8 partials for the new row, writeback)
// KIND 1: generic (qkvp partials, pcount)
// KIND 2: last-row-only (l2): only block with j == (S-1)&1 is active.
template<int KIND>
__global__ __launch_bounds__(256) void fused_layer_kernel(
    float* qkv0,
    const float* __restrict__ qkvp, size_t QS, int pcount,
    const float* __restrict__ bias3,
    const float* __restrict__ xin,
    const float* __restrict__ Wout, const float* __restrict__ ob,
    const float* __restrict__ ca,
    const float* __restrict__ g0, const float* __restrict__ b0,
    const float* __restrict__ g1, const float* __restrict__ b1,
    const float* __restrict__ w1, const float* __restrict__ b1f,
    const float* __restrict__ w2, const float* __restrict__ b2f,
    const float* __restrict__ g2, const float* __restrict__ bb2,
    float* __restrict__ aog, float* __restrict__ ybg,
    float* __restrict__ xout, int S, int istep)
{
    __shared__ float smem[16384];           // 64 KB: K[16][512] | V[16][512]
    float* Ksm = smem;
    float* Vsm = smem + 16 * E;
    float* Wss = smem;                      // P3 overlay: [64][128] on K region
    float* aoc = smem + 8192;               // P3 overlay: [8][64] on V region

    const int j = blockIdx.x, b = blockIdx.y, tid = threadIdx.x;
    if (KIND == 2 && j != ((S - 1) & 1)) return;
    const int R = (KIND == 2) ? 1 : ((S - j + 1) >> 1);
    if (R == 0) return;

    // ---------------- P1: stage K,V (+bias); KIND0 combines + writes back
    if (KIND == 0) {
        for (int e = tid; e < E3; e += 256) {
            const size_t pb = (size_t)b * E3 + e;
            float v = 0.f;
#pragma unroll
            for (int p = 0; p < 8; ++p) v += qkvp[(size_t)p * QS + pb];
            qkv0[((size_t)(istep * NB + b)) * E3 + e] = v;
            if (e >= E && e < 2 * E)  Ksm[istep * E + (e - E)]     = v + bias3[e];
            else if (e >= 2 * E)      Vsm[istep * E + (e - 2 * E)] = v + bias3[e];
        }
        for (int idx = tid; idx < istep * 2 * E; idx += 256) {
            const int s = idx >> 10, e = idx & 1023;
            const float v = qkv0[((size_t)(s * NB + b)) * E3 + E + e] + bias3[E + e];
            if (e < E) Ksm[s * E + e] = v;
            else       Vsm[s * E + (e - E)] = v;
        }
    } else {
        for (int idx = tid; idx < S * 2 * E; idx += 256) {
            const int s = idx >> 10, e = idx & 1023;
            const size_t base = ((size_t)(s * NB + b)) * E3 + E + e;
            float v = bias3[E + e];
            for (int p = 0; p < pcount; ++p) v += qkvp[(size_t)p * QS + base];
            if (e < E) Ksm[s * E + e] = v;
            else       Vsm[s * E + (e - E)] = v;
        }
    }
    __syncthreads();

    // ---------------- P2: attention (wave w -> heads 2w, 2w+1)
    const int w = tid >> 6, lane = tid & 63;
    for (int r = 0; r < R; ++r) {
        const int s = (KIND == 2) ? (S - 1) : (j + 2 * r);
#pragma unroll
        for (int hh = 0; hh < 2; ++hh) {
            const int h = w * 2 + hh;
            const int hd = h * 64 + lane;
            const size_t qb = ((size_t)(s * NB + b)) * E3 + hd;
            float q;
            if (KIND == 0) q = qkv0[qb] + bias3[hd];
            else {
                q = bias3[hd];
                for (int p = 0; p < pcount; ++p) q += qkvp[(size_t)p * QS + qb];
            }
            float sc[NT];
#pragma unroll
            for (int ki = 0; ki < NT; ++ki) {
                float p = 0.f;
                if (ki < S) {
                    p = q * Ksm[ki * E + hd];
                    p += __shfl_xor(p, 32); p += __shfl_xor(p, 16); p += __shfl_xor(p, 8);
                    p += __shfl_xor(p, 4);  p += __shfl_xor(p, 2);  p += __shfl_xor(p, 1);
                    p *= 0.125f;
                }
                sc[ki] = p;
            }
            float m = -1e30f;
#pragma unroll
            for (int ki = 0; ki < NT; ++ki) if (ki < S) m = fmaxf(m, sc[ki]);
            float sum = 0.f;
#pragma unroll
            for (int ki = 0; ki < NT; ++ki) if (ki < S) { sc[ki] = expf(sc[ki] - m); sum += sc[ki]; }
            const float inv = 1.0f / sum;
            float o = 0.f;
#pragma unroll
            for (int ki = 0; ki < NT; ++ki) if (ki < S) o += sc[ki] * Vsm[ki * E + hd];
            aog[((size_t)(s * NB + b)) * E + hd] = o * inv;
        }
    }
    __syncthreads();

    // ---------------- P3: y = ao @ Wout^T for assigned rows
    const int col_l = tid & 127;
    const int rg = tid >> 7;
    const int cst = tid >> 1;
    const int kh = (tid & 1) * 32;
    for (int nt = 0; nt < 4; ++nt) {
        float accp[4] = {0.f, 0.f, 0.f, 0.f};
        for (int kc = 0; kc < E; kc += 64) {
            __syncthreads();
            const float* wp = Wout + (size_t)(nt * 128 + cst) * E + kc + kh;
#pragma unroll
            for (int u = 0; u < 8; ++u) {
                const float4 w4 = *(const float4*)(wp + u * 4);
                Wss[(kh + u * 4 + 0) * 128 + cst] = w4.x;
                Wss[(kh + u * 4 + 1) * 128 + cst] = w4.y;
                Wss[(kh + u * 4 + 2) * 128 + cst] = w4.z;
                Wss[(kh + u * 4 + 3) * 128 + cst] = w4.w;
            }
#pragma unroll
            for (int q2 = 0; q2 < 2; ++q2) {
                const int idx = tid * 2 + q2;          // 0..511
                const int r = idx >> 6, kk = idx & 63;
                int s = (KIND == 2) ? (S - 1) : (j + 2 * r);
                if (s >= S) s = (KIND == 2) ? (S - 1) : j;
                aoc[idx] = aog[((size_t)(s * NB + b)) * E + kc + kk];
            }
            __syncthreads();
#pragma unroll
            for (int k4 = 0; k4 < 64; k4 += 4) {
                const float bw0 = Wss[(k4 + 0) * 128 + col_l];
                const float bw1 = Wss[(k4 + 1) * 128 + col_l];
                const float bw2 = Wss[(k4 + 2) * 128 + col_l];
                const float bw3 = Wss[(k4 + 3) * 128 + col_l];
#pragma unroll
                for (int rr = 0; rr < 4; ++rr) {
                    const float4 av = *(const float4*)&aoc[(rg * 4 + rr) * 64 + k4];
                    accp[rr] += av.x * bw0 + av.y * bw1 + av.z * bw2 + av.w * bw3;
                }
            }
        }
#pragma unroll
        for (int rr = 0; rr < 4; ++rr) {
            const int r = rg * 4 + rr;
            if (r < R) {
                const int s = (KIND == 2) ? (S - 1) : (j + 2 * r);
                ybg[((size_t)(s * NB + b)) * E + nt * 128 + col_l] = accp[rr];
            }
        }
    }
    __syncthreads();

    // ---------------- P4: epilogue per assigned row (one wave per row)
    for (int r = w; r < R; r += 4) {
        const int s = (KIND == 2) ? (S - 1) : (j + 2 * r);
        const size_t row = (size_t)(s * NB + b);
        const float* xr = xin + row * E;
        const float* yr = ybg + row * E;
        const float* cr = ca + (size_t)b * E;
        float v[8];
        float ss = 0.f;
#pragma unroll
        for (int jj = 0; jj < 8; ++jj) {
            const int e = jj * 64 + lane;
            const float y = xr[e] + ob[e] + yr[e];
            v[jj] = y; ss += y;
        }
#pragma unroll
        for (int off = 32; off; off >>= 1) ss += __shfl_xor(ss, off);
        float mean = ss * (1.0f / E);
        float vs = 0.f;
#pragma unroll
        for (int jj = 0; jj < 8; ++jj) { const float d = v[jj] - mean; vs += d * d; }
#pragma unroll
        for (int off = 32; off; off >>= 1) vs += __shfl_xor(vs, off);
        float rstd = rsqrtf(vs * (1.0f / E) + 1e-5f);
#pragma unroll
        for (int jj = 0; jj < 8; ++jj) {
            const int e = jj * 64 + lane;
            v[jj] = (v[jj] - mean) * rstd * g0[e] + b0[e] + cr[e];
        }
        ss = 0.f;
#pragma unroll
        for (int jj = 0; jj < 8; ++jj) ss += v[jj];
#pragma unroll
        for (int off = 32; off; off >>= 1) ss += __shfl_xor(ss, off);
        mean = ss * (1.0f / E);
        vs = 0.f;
#pragma unroll
        for (int jj = 0; jj < 8; ++jj) { const float d = v[jj] - mean; vs += d * d; }
#pragma unroll
        for (int off = 32; off; off >>= 1) vs += __shfl_xor(vs, off);
        rstd = rsqrtf(vs * (1.0f / E) + 1e-5f);
#pragma unroll
        for (int jj = 0; jj < 8; ++jj) {
            const int e = jj * 64 + lane;
            v[jj] = (v[jj] - mean) * rstd * g1[e] + b1[e];
        }
        float h[FF];
#pragma unroll
        for (int f = 0; f < FF; ++f) {
            float p = 0.f;
#pragma unroll
            for (int jj = 0; jj < 8; ++jj) p += v[jj] * w1[(size_t)f * E + jj * 64 + lane];
#pragma unroll
            for (int off = 32; off; off >>= 1) p += __shfl_xor(p, off);
            h[f] = fmaxf(p + b1f[f], 0.f);
        }
        float o[8];
#pragma unroll
        for (int jj = 0; jj < 8; ++jj) {
            const int e = jj * 64 + lane;
            float acc = b2f[e];
#pragma unroll
            for (int f4 = 0; f4 < FF / 4; ++f4) {
                const float4 w4 = *(const float4*)&w2[(size_t)e * FF + f4 * 4];
                acc += h[f4 * 4 + 0] * w4.x + h[f4 * 4 + 1] * w4.y +
                       h[f4 * 4 + 2] * w4.z + h[f4 * 4 + 3] * w4.w;
            }
            o[jj] = v[jj] + acc;
        }
        ss = 0.f;
#pragma unroll
        for (int jj = 0; jj < 8; ++jj) ss += o[jj];
#pragma unroll
        for (int off = 32; off; off >>= 1) ss += __shfl_xor(ss, off);
        mean = ss * (1.0f / E);
        vs = 0.f;
#pragma unroll
        for (int jj = 0; jj < 8; ++jj) { const float d = o[jj] - mean; vs += d * d; }
#pragma unroll
        for (int off = 32; off; off >>= 1) vs += __shfl_xor(vs, off);
        rstd = rsqrtf(vs * (1.0f / E) + 1e-5f);
#pragma unroll
        for (int jj = 0; jj < 8; ++jj) {
            const int e = jj * 64 + lane;
            xout[row * E + e] = (o[jj] - mean) * rstd * g2[e] + bb2[e];
        }
    }
}

// ------- softmax v2: sum 2 logit partials + bias, softmax+argmax in regs,
//         write probs, append emb[tok]+pe. One 1024-thread block per batch row.
__global__ __launch_bounds__(1024) void softmax_v2_kernel(
    const float* __restrict__ p0, const float* __restrict__ p1,
    const float* __restrict__ ob,
    float* __restrict__ probs_out, float* __restrict__ tok_out,
    const float* __restrict__ emb, const float* __restrict__ pe_row,
    float* __restrict__ tb_new, int step)
{
    const int b = blockIdx.x, t = threadIdx.x;
    const float* q0 = p0 + (size_t)b * NV;
    const float* q1 = p1 + (size_t)b * NV;
    float r[32];
    float vmax = -1e30f; int imax = 0x7fffffff;
#pragma unroll
    for (int j = 0; j < 32; ++j) {
        const int idx = j * 1024 + t;
        if (idx < NV) {
            const float v = ob[idx] + q0[idx] + q1[idx];
            r[j] = v;
            if (v > vmax) { vmax = v; imax = idx; }
        } else r[j] = -1e30f;
    }
    const int wid = t >> 6, lane = t & 63;
#pragma unroll
    for (int off = 32; off; off >>= 1) {
        const float ov = __shfl_xor(vmax, off);
        const int oi = __shfl_xor(imax, off);
        if (ov > vmax || (ov == vmax && oi < imax)) { vmax = ov; imax = oi; }
    }
    __shared__ float swv[16]; __shared__ int swi[16]; __shared__ float ssum[16];
    __shared__ float sbc[2];
    if (lane == 0) { swv[wid] = vmax; swi[wid] = imax; }
    __syncthreads();
    if (wid == 0) {
        float v = (lane < 16) ? swv[lane] : -1e30f;
        int ii = (lane < 16) ? swi[lane] : 0x7fffffff;
#pragma unroll
        for (int off = 8; off; off >>= 1) {
            const float ov = __shfl_xor(v, off);
            const int oi = __shfl_xor(ii, off);
            if (ov > v || (ov == v && oi < ii)) { v = ov; ii = oi; }
        }
        if (lane == 0) { sbc[0] = v; swi[0] = ii; }
    }
    __syncthreads();
    const float m = sbc[0];
    const int tok = swi[0];
    float psum = 0.f;
#pragma unroll
    for (int j = 0; j < 32; ++j) {
        const int idx = j * 1024 + t;
        if (idx < NV) { r[j] = expf(r[j] - m); psum += r[j]; }
    }
#pragma unroll
    for (int off = 32; off; off >>= 1) psum += __shfl_xor(psum, off);
    if (lane == 0) ssum[wid] = psum;
    __syncthreads();
    if (t == 0) {
        float s = 0.f;
        for (int ww = 0; ww < 16; ++ww) s += ssum[ww];
        sbc[1] = 1.0f / s;
    }
    __syncthreads();
    const float inv = sbc[1];
    float* P = probs_out + (size_t)b * NV;
#pragma unroll
    for (int j = 0; j < 32; ++j) {
        const int idx = j * 1024 + t;
        if (idx < NV) P[idx] = r[j] * inv;
    }
    if (t == 0) tok_out[(size_t)b * NT + step] = (float)tok;
    if (t < E) tb_new[(size_t)b * E + t] = emb[(size_t)tok * E + t] + pe_row[t];
}

// ================================================================ host
extern "C" void kernel_launch(void* const* d_in, const int* in_sizes, int n_in,
                              void* d_out, int out_size, void* d_ws, size_t ws_size,
                              hipStream_t stream) {
    const float* cur_room = (const float*)d_in[0];
    const float* emb      = (const float*)d_in[1];
    const float* sa_in_w  = (const float*)d_in[2];
    const float* sa_in_b  = (const float*)d_in[3];
    const float* sa_out_w = (const float*)d_in[4];
    const float* sa_out_b = (const float*)d_in[5];
    const float* ca_in_w  = (const float*)d_in[6];
    const float* ca_in_b  = (const float*)d_in[7];
    const float* ca_out_w = (const float*)d_in[8];
    const float* ca_out_b = (const float*)d_in[9];
    const float* ff1_w    = (const float*)d_in[10];
    const float* ff1_b    = (const float*)d_in[11];
    const float* ff2_w    = (const float*)d_in[12];
    const float* ff2_b    = (const float*)d_in[13];
    const float* ln_g     = (const float*)d_in[14];
    const float* ln_b     = (const float*)d_in[15];
    const float* out_w    = (const float*)d_in[16];
    const float* out_b    = (const float*)d_in[17];
    float* out = (float*)d_out;

    float* ws = (float*)d_ws;
    float* pe       = ws;
    float* ca_const = pe + 16 * E;
    float* tokb     = ca_const + (size_t)NL * NB * E;
    float* x        = tokb + (size_t)17 * NB * E;
    float* qkv0     = x + (size_t)NT * NB * E;
    float* qkv0p    = qkv0 + (size_t)NT * NB * E3;
    float* qkvp     = qkv0p + (size_t)8 * NB * E3;
    float* aog      = qkvp + (size_t)32 * NB * E3;
    float* ybg      = aog + (size_t)NT * NB * E;
    float* vocp     = ybg + (size_t)NT * NB * E;

    pe_init_kernel<<<16, 256, 0, stream>>>(pe);
    init_tok_kernel<<<NB, 256, 0, stream>>>(tokb, emb);
    ca_setup_kernel<<<dim3(NB, NL), 256, 0, stream>>>(
        cur_room, ca_in_w, ca_in_b, ca_out_w, ca_out_b, ca_const);

    const size_t QS0 = (size_t)NB * E3;

    for (int i = 0; i < NT; ++i) {
        const int S = i + 1;
        const int M = S * NB;
        const size_t QSM = (size_t)M * E3;
        const int z = (S <= 2) ? 8 : (S <= 8) ? 4 : 2;

        // ---- layer 0: incremental qkv (new 128 rows), split-K=8
        gemm_v4_kernel<<<dim3(E3 / 128, 1, 8), 256, 0, stream>>>(
            tokb + (size_t)i * NB * E, sa_in_w, qkv0p, E3, E, 64, QS0, 0);
        fused_layer_kernel<0><<<dim3(2, NB), 256, 0, stream>>>(
            qkv0, qkv0p, QS0, 8, sa_in_b,
            tokb, sa_out_w, sa_out_b, ca_const,
            ln_g + 0 * E, ln_b + 0 * E, ln_g + 1 * E, ln_b + 1 * E,
            ff1_w, ff1_b, ff2_w, ff2_b, ln_g + 2 * E, ln_b + 2 * E,
            aog, ybg, x, S, i);

        // ---- layer 1
        gemm_v4_kernel<<<dim3(E3 / 128, S, z), 256, 0, stream>>>(
            x, sa_in_w + (size_t)E3 * E, qkvp, E3, E, E / z, QSM, 0);
        fused_layer_kernel<1><<<dim3(2, NB), 256, 0, stream>>>(
            qkv0, qkvp, QSM, z, sa_in_b + E3,
            x, sa_out_w + (size_t)E * E, sa_out_b + E, ca_const + (size_t)NB * E,
            ln_g + 3 * E, ln_b + 3 * E, ln_g + 4 * E, ln_b + 4 * E,
            ff1_w + FF * E, ff1_b + FF, ff2_w + (size_t)E * FF, ff2_b + E,
            ln_g + 5 * E, ln_b + 5 * E,
            aog, ybg, x, S, i);

        // ---- layer 2 (only last position consumed downstream)
        gemm_v4_kernel<<<dim3(E3 / 128, S, z), 256, 0, stream>>>(
            x, sa_in_w + (size_t)2 * E3 * E, qkvp, E3, E, E / z, QSM, (S - 1) * NB);
        fused_layer_kernel<2><<<dim3(2, NB), 256, 0, stream>>>(
            qkv0, qkvp, QSM, z, sa_in_b + 2 * E3,
            x, sa_out_w + (size_t)2 * E * E, sa_out_b + 2 * E, ca_const + (size_t)2 * NB * E,
            ln_g + 6 * E, ln_b + 6 * E, ln_g + 7 * E, ln_b + 7 * E,
            ff1_w + 2 * FF * E, ff1_b + 2 * FF, ff2_w + (size_t)2 * E * FF, ff2_b + 2 * E,
            ln_g + 8 * E, ln_b + 8 * E,
            aog, ybg, x, S, i);

        // ---- vocab projection of last position (split-K=2) + fused softmax
        gemm_v4_kernel<<<dim3(NV / 128, 1, 2), 256, 0, stream>>>(
            x + (size_t)i * NB * E, out_w, vocp, NV, E, 256, (size_t)NB * NV, 0);
        softmax_v2_kernel<<<NB, 1024, 0, stream>>>(
            vocp, vocp + (size_t)NB * NV, out_b,
            out + 2048 + (size_t)i * NB * NV, out,
            emb, pe + (size_t)i * E, tokb + (size_t)S * NB * E, i);
    }
}

// Round 6
// 5784.632 us; speedup vs baseline: 2.1112x; 2.1112x over previous
//
#include <hip/hip_runtime.h>
#include <math.h>

#define E   512
#define E3  1536
#define NH  8
#define FF  32
#define NL  3
#define NV  32000
#define NB  128
#define NT  16

// ---------------------------------------------------------------- pe table
__global__ void pe_init_kernel(float* __restrict__ pe) {
    int i = blockIdx.x;
    for (int e = threadIdx.x; e < E; e += blockDim.x) {
        int k = e >> 1;
        double dv = exp((double)(2 * k) * (-log(10000.0) / (double)E));
        double arg = (double)i * dv;
        pe[i * E + e] = (e & 1) ? (float)cos(arg) : (float)sin(arg);
    }
}

// ------------------------------------------------------- tok_before row 0
__global__ void init_tok_kernel(float* __restrict__ tb, const float* __restrict__ emb) {
    int b = blockIdx.x;
    for (int e = threadIdx.x; e < E; e += blockDim.x)
        tb[(size_t)b * E + e] = emb[(size_t)1 * E + e];  // SOS = 1
}

// ---------------------------------------------------------------- GEMM v3
// C_partial[z] = A[M,K-slice] @ W[N,K-slice]^T (+bias). Tile 64x128, 256 thr,
// 4x8/thread. M%64==0, N%128==0, KC%16==0. Partial z -> C + z*CS.
// Q-tiles (n0 < E) with m0 < skipm are skipped.
template<bool ADD_BIAS>
__global__ __launch_bounds__(256) void gemm_v3_kernel(
    const float* __restrict__ A, const float* __restrict__ W,
    const float* __restrict__ bias, float* __restrict__ C,
    int N, int K, int KC, size_t CS, int skipm)
{
    const int m0 = blockIdx.y * 64;
    const int n0 = blockIdx.x * 128;
    if (n0 < E && m0 < skipm) return;
    __shared__ float As[16][68];
    __shared__ float Bs[16][132];
    const int tid = threadIdx.x;
    const int kc0 = blockIdx.z * KC;
    const int tx = tid & 15;
    const int ty = tid >> 4;
    const int sr = tid >> 2;
    const int sc = (tid & 3) * 4;

    const float* Ap  = A + (size_t)(m0 + sr) * K + kc0 + sc;
    const float* Wp0 = W + (size_t)(n0 + sr) * K + kc0 + sc;
    const float* Wp1 = W + (size_t)(n0 + 64 + sr) * K + kc0 + sc;

    float4 pa  = *(const float4*)Ap;
    float4 pb0 = *(const float4*)Wp0;
    float4 pb1 = *(const float4*)Wp1;

    float acc[4][8] = {};
    const int nkt = KC >> 4;
    for (int kt = 0; kt < nkt; ++kt) {
        __syncthreads();
        As[sc + 0][sr] = pa.x;  As[sc + 1][sr] = pa.y;
        As[sc + 2][sr] = pa.z;  As[sc + 3][sr] = pa.w;
        Bs[sc + 0][sr] = pb0.x; Bs[sc + 1][sr] = pb0.y;
        Bs[sc + 2][sr] = pb0.z; Bs[sc + 3][sr] = pb0.w;
        Bs[sc + 0][64 + sr] = pb1.x; Bs[sc + 1][64 + sr] = pb1.y;
        Bs[sc + 2][64 + sr] = pb1.z; Bs[sc + 3][64 + sr] = pb1.w;
        __syncthreads();
        if (kt + 1 < nkt) {
            const int off = 16 * (kt + 1);
            pa  = *(const float4*)(Ap + off);
            pb0 = *(const float4*)(Wp0 + off);
            pb1 = *(const float4*)(Wp1 + off);
        }
#pragma unroll
        for (int k = 0; k < 16; ++k) {
            float a[4], b[8];
            *(float4*)&a[0] = *(const float4*)&As[k][ty * 4];
            *(float4*)&b[0] = *(const float4*)&Bs[k][tx * 4];
            *(float4*)&b[4] = *(const float4*)&Bs[k][64 + tx * 4];
#pragma unroll
            for (int i = 0; i < 4; ++i)
#pragma unroll
                for (int j = 0; j < 8; ++j)
                    acc[i][j] += a[i] * b[j];
        }
    }
    float* Co = C + (size_t)blockIdx.z * CS;
#pragma unroll
    for (int i = 0; i < 4; ++i) {
        const int m = m0 + ty * 4 + i;
#pragma unroll
        for (int cj = 0; cj < 2; ++cj) {
            const int n = n0 + cj * 64 + tx * 4;
            float4 o;
            o.x = acc[i][cj * 4 + 0];
            o.y = acc[i][cj * 4 + 1];
            o.z = acc[i][cj * 4 + 2];
            o.w = acc[i][cj * 4 + 3];
            if (ADD_BIAS) {
                const float4 bv = *(const float4*)&bias[n];
                o.x += bv.x; o.y += bv.y; o.z += bv.z; o.w += bv.w;
            }
            *(float4*)&Co[(size_t)m * N + n] = o;
        }
    }
}

// ---------------------------------------------------------------- GEMM v4
// C_partial[z] = A @ W^T, tile 128x128, 256 thr, 8x8/thread. M%128==0,
// N%128==0, KC%16==0. Q-tiles (n0 < E) with m0 < skipm skipped.
__global__ __launch_bounds__(256) void gemm_v4_kernel(
    const float* __restrict__ A, const float* __restrict__ W,
    float* __restrict__ C, int N, int K, int KC, size_t CS, int skipm)
{
    const int n0 = blockIdx.x * 128;
    const int m0 = blockIdx.y * 128;
    if (n0 < E && m0 < skipm) return;
    __shared__ float As[16][132];
    __shared__ float Bs[16][132];
    const int tid = threadIdx.x;
    const int kc0 = blockIdx.z * KC;
    const int tx = tid & 15, ty = tid >> 4;
    const int sr = tid >> 1;
    const int sc = (tid & 1) * 8;

    const float* Ap = A + (size_t)(m0 + sr) * K + kc0 + sc;
    const float* Wp = W + (size_t)(n0 + sr) * K + kc0 + sc;
    float4 pa0 = *(const float4*)Ap;
    float4 pa1 = *(const float4*)(Ap + 4);
    float4 pb0 = *(const float4*)Wp;
    float4 pb1 = *(const float4*)(Wp + 4);

    float acc[8][8] = {};
    const int nkt = KC >> 4;
    for (int kt = 0; kt < nkt; ++kt) {
        __syncthreads();
        As[sc + 0][sr] = pa0.x; As[sc + 1][sr] = pa0.y; As[sc + 2][sr] = pa0.z; As[sc + 3][sr] = pa0.w;
        As[sc + 4][sr] = pa1.x; As[sc + 5][sr] = pa1.y; As[sc + 6][sr] = pa1.z; As[sc + 7][sr] = pa1.w;
        Bs[sc + 0][sr] = pb0.x; Bs[sc + 1][sr] = pb0.y; Bs[sc + 2][sr] = pb0.z; Bs[sc + 3][sr] = pb0.w;
        Bs[sc + 4][sr] = pb1.x; Bs[sc + 5][sr] = pb1.y; Bs[sc + 6][sr] = pb1.z; Bs[sc + 7][sr] = pb1.w;
        __syncthreads();
        if (kt + 1 < nkt) {
            const int off = 16 * (kt + 1);
            pa0 = *(const float4*)(Ap + off);
            pa1 = *(const float4*)(Ap + off + 4);
            pb0 = *(const float4*)(Wp + off);
            pb1 = *(const float4*)(Wp + off + 4);
        }
#pragma unroll
        for (int k = 0; k < 16; ++k) {
            float a[8], b[8];
            *(float4*)&a[0] = *(const float4*)&As[k][ty * 4];
            *(float4*)&a[4] = *(const float4*)&As[k][64 + ty * 4];
            *(float4*)&b[0] = *(const float4*)&Bs[k][tx * 4];
            *(float4*)&b[4] = *(const float4*)&Bs[k][64 + tx * 4];
#pragma unroll
            for (int i = 0; i < 8; ++i)
#pragma unroll
                for (int jj = 0; jj < 8; ++jj)
                    acc[i][jj] += a[i] * b[jj];
        }
    }
    float* Co = C + (size_t)blockIdx.z * CS;
#pragma unroll
    for (int ih = 0; ih < 2; ++ih)
#pragma unroll
        for (int i = 0; i < 4; ++i) {
            const int m = m0 + ih * 64 + ty * 4 + i;
#pragma unroll
            for (int jh = 0; jh < 2; ++jh) {
                const int n = n0 + jh * 64 + tx * 4;
                float4 o;
                o.x = acc[ih * 4 + i][jh * 4 + 0];
                o.y = acc[ih * 4 + i][jh * 4 + 1];
                o.z = acc[ih * 4 + i][jh * 4 + 2];
                o.w = acc[ih * 4 + i][jh * 4 + 3];
                *(float4*)&Co[(size_t)m * N + n] = o;
            }
        }
}

// ---------------- combine split-K partials: dst[i] = sum_p src[p*PS + i]
__global__ __launch_bounds__(256) void combine4_kernel(
    const float* __restrict__ src, size_t PS, int pcount, float* __restrict__ dst)
{
    const int i = (blockIdx.x * 256 + threadIdx.x) * 4;
    float4 s = *(const float4*)&src[i];
    for (int p = 1; p < pcount; ++p) {
        const float4 a = *(const float4*)&src[(size_t)p * PS + i];
        s.x += a.x; s.y += a.y; s.z += a.z; s.w += a.w;
    }
    *(float4*)&dst[i] = s;
}

// -------------------------------------------------------- self attention
// Sums pcount partials + bias while staging. qi in [qstart, S).
__global__ __launch_bounds__(128) void attn_kernel(
    const float* __restrict__ qkv, size_t QS, int pcount,
    const float* __restrict__ bias,
    float* __restrict__ o, int S, int qstart)
{
    const int b = blockIdx.x >> 3;
    const int h = blockIdx.x & 7;
    __shared__ float Ks[16][64];
    __shared__ float Vs[16][64];
    const int tid = threadIdx.x;
    for (int idx = tid; idx < S * 64; idx += 128) {
        int s = idx >> 6, d = idx & 63;
        size_t base = ((size_t)(s * NB + b)) * E3 + h * 64 + d;
        float kk = bias[E + h * 64 + d];
        float vv = bias[2 * E + h * 64 + d];
        for (int p = 0; p < pcount; ++p) {
            kk += qkv[(size_t)p * QS + base + E];
            vv += qkv[(size_t)p * QS + base + 2 * E];
        }
        Ks[s][d] = kk;
        Vs[s][d] = vv;
    }
    __syncthreads();
    const int wid = tid >> 6, lane = tid & 63;
    const float bq = bias[h * 64 + lane];
    for (int qi = qstart + wid; qi < S; qi += 2) {
        size_t qbase = ((size_t)(qi * NB + b)) * E3 + h * 64 + lane;
        float qd = bq;
        for (int p = 0; p < pcount; ++p) qd += qkv[(size_t)p * QS + qbase];
        float sc[16];
#pragma unroll
        for (int ki = 0; ki < 16; ++ki) {
            float p = 0.f;
            if (ki < S) {
                p = qd * Ks[ki][lane];
#pragma unroll
                for (int off = 32; off; off >>= 1) p += __shfl_xor(p, off);
                p *= 0.125f;
            }
            sc[ki] = p;
        }
        float m = -1e30f;
#pragma unroll
        for (int ki = 0; ki < 16; ++ki) if (ki < S) m = fmaxf(m, sc[ki]);
        float sum = 0.f;
#pragma unroll
        for (int ki = 0; ki < 16; ++ki) if (ki < S) { sc[ki] = expf(sc[ki] - m); sum += sc[ki]; }
        float inv = 1.0f / sum;
        float acc = 0.f;
#pragma unroll
        for (int ki = 0; ki < 16; ++ki) if (ki < S) acc += sc[ki] * Vs[ki][lane];
        o[((size_t)(qi * NB + b)) * E + h * 64 + lane] = acc * inv;
    }
}

// ---- fused epilogue: y = sum(ypartials)+ob; LN0(xin+y); +ca; LN1; FFN; LN2
__global__ __launch_bounds__(256) void epilogue_kernel(
    const float* __restrict__ xin,
    const float* __restrict__ yp, size_t YS, int pcount,
    const float* __restrict__ ob,
    const float* __restrict__ ca,
    const float* __restrict__ g0, const float* __restrict__ b0,
    const float* __restrict__ g1, const float* __restrict__ b1,
    const float* __restrict__ w1, const float* __restrict__ b1f,
    const float* __restrict__ w2, const float* __restrict__ b2f,
    const float* __restrict__ g2, const float* __restrict__ bb2,
    float* __restrict__ xout, int rows)
{
    const int wid = threadIdx.x >> 6, lane = threadIdx.x & 63;
    const int row = blockIdx.x * 4 + wid;
    if (row >= rows) return;
    const float* xr = xin + (size_t)row * E;
    const float* cr = ca + (size_t)(row & (NB - 1)) * E;
    float v[8];
    float s = 0.f;
#pragma unroll
    for (int j = 0; j < 8; ++j) {
        int e = j * 64 + lane;
        float y = xr[e] + ob[e];
        for (int p = 0; p < pcount; ++p) y += yp[(size_t)p * YS + (size_t)row * E + e];
        v[j] = y; s += y;
    }
#pragma unroll
    for (int off = 32; off; off >>= 1) s += __shfl_xor(s, off);
    float mean = s * (1.0f / E);
    float vs = 0.f;
#pragma unroll
    for (int j = 0; j < 8; ++j) { float d = v[j] - mean; vs += d * d; }
#pragma unroll
    for (int off = 32; off; off >>= 1) vs += __shfl_xor(vs, off);
    float rstd = rsqrtf(vs * (1.0f / E) + 1e-5f);
#pragma unroll
    for (int j = 0; j < 8; ++j) {
        int e = j * 64 + lane;
        v[j] = (v[j] - mean) * rstd * g0[e] + b0[e] + cr[e];
    }
    s = 0.f;
#pragma unroll
    for (int j = 0; j < 8; ++j) s += v[j];
#pragma unroll
    for (int off = 32; off; off >>= 1) s += __shfl_xor(s, off);
    mean = s * (1.0f / E);
    vs = 0.f;
#pragma unroll
    for (int j = 0; j < 8; ++j) { float d = v[j] - mean; vs += d * d; }
#pragma unroll
    for (int off = 32; off; off >>= 1) vs += __shfl_xor(vs, off);
    rstd = rsqrtf(vs * (1.0f / E) + 1e-5f);
#pragma unroll
    for (int j = 0; j < 8; ++j) {
        int e = j * 64 + lane;
        v[j] = (v[j] - mean) * rstd * g1[e] + b1[e];
    }
    float h[FF];
#pragma unroll
    for (int f = 0; f < FF; ++f) {
        float p = 0.f;
#pragma unroll
        for (int j = 0; j < 8; ++j) p += v[j] * w1[(size_t)f * E + j * 64 + lane];
#pragma unroll
        for (int off = 32; off; off >>= 1) p += __shfl_xor(p, off);
        h[f] = fmaxf(p + b1f[f], 0.f);
    }
    float o[8];
#pragma unroll
    for (int j = 0; j < 8; ++j) {
        int e = j * 64 + lane;
        float acc = b2f[e];
#pragma unroll
        for (int f4 = 0; f4 < FF / 4; ++f4) {
            float4 w4 = *(const float4*)&w2[(size_t)e * FF + f4 * 4];
            acc += h[f4 * 4 + 0] * w4.x + h[f4 * 4 + 1] * w4.y +
                   h[f4 * 4 + 2] * w4.z + h[f4 * 4 + 3] * w4.w;
        }
        o[j] = v[j] + acc;
    }
    s = 0.f;
#pragma unroll
    for (int j = 0; j < 8; ++j) s += o[j];
#pragma unroll
    for (int off = 32; off; off >>= 1) s += __shfl_xor(s, off);
    mean = s * (1.0f / E);
    vs = 0.f;
#pragma unroll
    for (int j = 0; j < 8; ++j) { float d = o[j] - mean; vs += d * d; }
#pragma unroll
    for (int off = 32; off; off >>= 1) vs += __shfl_xor(vs, off);
    rstd = rsqrtf(vs * (1.0f / E) + 1e-5f);
#pragma unroll
    for (int j = 0; j < 8; ++j) {
        int e = j * 64 + lane;
        xout[(size_t)row * E + e] = (o[j] - mean) * rstd * g2[e] + bb2[e];
    }
}

// ------- softmax v2: sum 2 logit partials + bias, softmax+argmax in regs
__global__ __launch_bounds__(1024) void softmax_v2_kernel(
    const float* __restrict__ p0, const float* __restrict__ p1,
    const float* __restrict__ ob,
    float* __restrict__ probs_out, float* __restrict__ tok_out,
    const float* __restrict__ emb, const float* __restrict__ pe_row,
    float* __restrict__ tb_new, int step)
{
    const int b = blockIdx.x, t = threadIdx.x;
    const float* q0 = p0 + (size_t)b * NV;
    const float* q1 = p1 + (size_t)b * NV;
    float r[32];
    float vmax = -1e30f; int imax = 0x7fffffff;
#pragma unroll
    for (int j = 0; j < 32; ++j) {
        const int idx = j * 1024 + t;
        if (idx < NV) {
            const float v = ob[idx] + q0[idx] + q1[idx];
            r[j] = v;
            if (v > vmax) { vmax = v; imax = idx; }
        } else r[j] = -1e30f;
    }
    const int wid = t >> 6, lane = t & 63;
#pragma unroll
    for (int off = 32; off; off >>= 1) {
        const float ov = __shfl_xor(vmax, off);
        const int oi = __shfl_xor(imax, off);
        if (ov > vmax || (ov == vmax && oi < imax)) { vmax = ov; imax = oi; }
    }
    __shared__ float swv[16]; __shared__ int swi[16]; __shared__ float ssum[16];
    __shared__ float sbc[2];
    if (lane == 0) { swv[wid] = vmax; swi[wid] = imax; }
    __syncthreads();
    if (wid == 0) {
        float v = (lane < 16) ? swv[lane] : -1e30f;
        int ii = (lane < 16) ? swi[lane] : 0x7fffffff;
#pragma unroll
        for (int off = 8; off; off >>= 1) {
            const float ov = __shfl_xor(v, off);
            const int oi = __shfl_xor(ii, off);
            if (ov > v || (ov == v && oi < ii)) { v = ov; ii = oi; }
        }
        if (lane == 0) { sbc[0] = v; swi[0] = ii; }
    }
    __syncthreads();
    const float m = sbc[0];
    const int tok = swi[0];
    float psum = 0.f;
#pragma unroll
    for (int j = 0; j < 32; ++j) {
        const int idx = j * 1024 + t;
        if (idx < NV) { r[j] = expf(r[j] - m); psum += r[j]; }
    }
#pragma unroll
    for (int off = 32; off; off >>= 1) psum += __shfl_xor(psum, off);
    if (lane == 0) ssum[wid] = psum;
    __syncthreads();
    if (t == 0) {
        float s = 0.f;
        for (int ww = 0; ww < 16; ++ww) s += ssum[ww];
        sbc[1] = 1.0f / s;
    }
    __syncthreads();
    const float inv = sbc[1];
    float* P = probs_out + (size_t)b * NV;
#pragma unroll
    for (int j = 0; j < 32; ++j) {
        const int idx = j * 1024 + t;
        if (idx < NV) P[idx] = r[j] * inv;
    }
    if (t == 0) tok_out[(size_t)b * NT + step] = (float)tok;
    if (t < E) tb_new[(size_t)b * E + t] = emb[(size_t)tok * E + t] + pe_row[t];
}

// ================================================================ host
extern "C" void kernel_launch(void* const* d_in, const int* in_sizes, int n_in,
                              void* d_out, int out_size, void* d_ws, size_t ws_size,
                              hipStream_t stream) {
    const float* cur_room = (const float*)d_in[0];
    const float* emb      = (const float*)d_in[1];
    const float* sa_in_w  = (const float*)d_in[2];
    const float* sa_in_b  = (const float*)d_in[3];
    const float* sa_out_w = (const float*)d_in[4];
    const float* sa_out_b = (const float*)d_in[5];
    const float* ca_in_w  = (const float*)d_in[6];
    const float* ca_in_b  = (const float*)d_in[7];
    const float* ca_out_w = (const float*)d_in[8];
    const float* ca_out_b = (const float*)d_in[9];
    const float* ff1_w    = (const float*)d_in[10];
    const float* ff1_b    = (const float*)d_in[11];
    const float* ff2_w    = (const float*)d_in[12];
    const float* ff2_b    = (const float*)d_in[13];
    const float* ln_g     = (const float*)d_in[14];
    const float* ln_b     = (const float*)d_in[15];
    const float* out_w    = (const float*)d_in[16];
    const float* out_b    = (const float*)d_in[17];
    float* out = (float*)d_out;

    float* ws = (float*)d_ws;
    float* pe       = ws;
    float* ca_const = pe + 16 * E;
    float* hv       = ca_const + (size_t)NL * NB * E;
    float* tokb     = hv + (size_t)NB * E;
    float* x        = tokb + (size_t)17 * NB * E;
    float* qkv0p    = x + (size_t)NT * NB * E;
    float* qkv0     = qkv0p + (size_t)8 * NB * E3;
    float* qkvp     = qkv0 + (size_t)NT * NB * E3;
    float* attn_o   = qkvp + (size_t)32 * NB * E3;
    float* ypart    = attn_o + (size_t)NT * NB * E;
    float* vocp     = ypart + (size_t)8 * NT * NB * E;

    pe_init_kernel<<<16, 256, 0, stream>>>(pe);
    init_tok_kernel<<<NB, 256, 0, stream>>>(tokb, emb);

    // cross-attention constants (KV len 1 -> softmax == 1 -> V-proj only)
    for (int l = 0; l < NL; ++l) {
        const float* wv = ca_in_w + ((size_t)l * E3 + 2 * E) * E;
        const float* bv = ca_in_b + (size_t)l * E3 + 2 * E;
        gemm_v3_kernel<true><<<dim3(E / 128, 2, 1), 256, 0, stream>>>(
            cur_room, wv, bv, hv, E, E, E, 0, 0);
        gemm_v3_kernel<true><<<dim3(E / 128, 2, 1), 256, 0, stream>>>(
            hv, ca_out_w + (size_t)l * E * E, ca_out_b + (size_t)l * E,
            ca_const + (size_t)l * NB * E, E, E, E, 0, 0);
    }

    const size_t QS0 = (size_t)NB * E3;

    for (int i = 0; i < NT; ++i) {
        const int S = i + 1;
        const int M = S * NB;
        const size_t QSM = (size_t)M * E3;
        const size_t YSM = (size_t)M * E;

        // ---- layer 0: incremental qkv (new 128 rows), split-K=8 + combine
        gemm_v3_kernel<false><<<dim3(E3 / 128, 2, 8), 256, 0, stream>>>(
            tokb + (size_t)i * NB * E, sa_in_w, nullptr, qkv0p, E3, E, 64, QS0, 0);
        combine4_kernel<<<(NB * E3) / 1024, 256, 0, stream>>>(
            qkv0p, QS0, 8, qkv0 + (size_t)i * NB * E3);

        const int z_out = (S <= 8) ? 8 : 4;
        for (int l = 0; l < NL; ++l) {
            const float* xin = (l == 0) ? tokb : x;
            const float* qkv_l;
            size_t QS; int pcount;
            const int skipm = (l == 2) ? (S - 1) * NB : 0;
            if (l == 0) {
                qkv_l = qkv0; QS = 0; pcount = 1;
            } else {
                const float* wq = sa_in_w + (size_t)l * E3 * E;
                if (S <= 4) {
                    const int z = (S <= 2) ? 8 : 4;
                    gemm_v3_kernel<false><<<dim3(E3 / 128, 2 * S, z), 256, 0, stream>>>(
                        x, wq, nullptr, qkvp, E3, E, E / z, QSM, skipm);
                    pcount = z;
                } else {
                    const int z = (S <= 8) ? 4 : 2;
                    gemm_v4_kernel<<<dim3(E3 / 128, S, z), 256, 0, stream>>>(
                        x, wq, qkvp, E3, E, E / z, QSM, skipm);
                    pcount = z;
                }
                qkv_l = qkvp; QS = QSM;
            }
            const int qstart = (l == 2) ? S - 1 : 0;
            attn_kernel<<<NB * NH, 128, 0, stream>>>(
                qkv_l, QS, pcount, sa_in_b + (size_t)l * E3, attn_o, S, qstart);

            if (l == 2) {
                // out-proj + epilogue on last position only (M = 128)
                gemm_v3_kernel<false><<<dim3(E / 128, 2, 8), 256, 0, stream>>>(
                    attn_o + (size_t)(S - 1) * NB * E, sa_out_w + (size_t)l * E * E,
                    nullptr, ypart, E, E, 64, (size_t)NB * E, 0);
                epilogue_kernel<<<32, 256, 0, stream>>>(
                    xin + (size_t)(S - 1) * NB * E, ypart, (size_t)NB * E, 8,
                    sa_out_b + (size_t)l * E, ca_const + (size_t)l * NB * E,
                    ln_g + (size_t)(l * 3 + 0) * E, ln_b + (size_t)(l * 3 + 0) * E,
                    ln_g + (size_t)(l * 3 + 1) * E, ln_b + (size_t)(l * 3 + 1) * E,
                    ff1_w + (size_t)l * FF * E, ff1_b + (size_t)l * FF,
                    ff2_w + (size_t)l * E * FF, ff2_b + (size_t)l * E,
                    ln_g + (size_t)(l * 3 + 2) * E, ln_b + (size_t)(l * 3 + 2) * E,
                    x + (size_t)(S - 1) * NB * E, NB);
            } else {
                gemm_v3_kernel<false><<<dim3(E / 128, 2 * S, z_out), 256, 0, stream>>>(
                    attn_o, sa_out_w + (size_t)l * E * E, nullptr,
                    ypart, E, E, E / z_out, YSM, 0);
                epilogue_kernel<<<S * 32, 256, 0, stream>>>(
                    xin, ypart, YSM, z_out,
                    sa_out_b + (size_t)l * E, ca_const + (size_t)l * NB * E,
                    ln_g + (size_t)(l * 3 + 0) * E, ln_b + (size_t)(l * 3 + 0) * E,
                    ln_g + (size_t)(l * 3 + 1) * E, ln_b + (size_t)(l * 3 + 1) * E,
                    ff1_w + (size_t)l * FF * E, ff1_b + (size_t)l * FF,
                    ff2_w + (size_t)l * E * FF, ff2_b + (size_t)l * E,
                    ln_g + (size_t)(l * 3 + 2) * E, ln_b + (size_t)(l * 3 + 2) * E,
                    x, M);
            }
        }
        // ---- vocab projection (last position, M=128) split-K=2 + softmax
        gemm_v4_kernel<<<dim3(NV / 128, 1, 2), 256, 0, stream>>>(
            x + (size_t)i * NB * E, out_w, vocp, NV, E, 256, (size_t)NB * NV, 0);
        softmax_v2_kernel<<<NB, 1024, 0, stream>>>(
            vocp, vocp + (size_t)NB * NV, out_b,
            out + 2048 + (size_t)i * NB * NV, out,
            emb, pe + (size_t)i * E, tokb + (size_t)S * NB * E, i);
    }
}